// Round 1
// 72.997 us; speedup vs baseline: 1.1911x; 1.1911x over previous
//
#include <hip/hip_runtime.h>
#include <math.h>

namespace {
constexpr int B = 4, P = 64, V = 32, D = 256;
constexpr float MARGIN = 0.1f;
constexpr float L_REG = 0.1f, L_SIGMA = 0.05f;
constexpr int NRED = 16;  // mu/sigma partial-reduction blocks (4 per batch), run first

// ws layout: [0, B*P*P)            costs (B,P,P)
//            [B*P*P, B*P*P+NRED*2) mu/sigma partials: (block)*2 + {reg,sig}

// Blocks [0,NRED): mu/sigma partial reduction (overlaps with costs compute).
// Blocks [NRED, NRED+2048): one wave per (b,g,p-pair); lanes 0-31 -> p0,
// lanes 32-63 -> p1, r = lane&31. gt via register cache + 2 shuffles/step;
// pred via half-uniform global_load_dwordx2 (broadcast, L1-hit). Wave-uniform
// dynamic trip count loopN = max over halves of mn (~18 avg vs 32).
__global__ __launch_bounds__(256) void costs_kernel(
    const float* __restrict__ gt,    // (B,P,V,2)
    const float* __restrict__ pred,  // (B,P,V,2)
    const int*   __restrict__ mask,  // (B,P,V)
    const int*   __restrict__ cls,   // (B,P)
    const float* __restrict__ mu,    // (B,P,D)
    const float* __restrict__ sigma, // (B,P,D)
    float*       __restrict__ ws)
{
    float* costs    = ws;
    float* partials = ws + B * P * P;

    if (blockIdx.x < NRED) {
        // 4 blocks per batch, each reduces 1/4 of mu (16 KB) + sigma (16 KB).
        const int b = blockIdx.x >> 2;
        const int j = blockIdx.x & 3;
        const float4* mub = (const float4*)(mu    + (size_t)b * P * D) + j * 1024;
        const float4* sgb = (const float4*)(sigma + (size_t)b * P * D) + j * 1024;
        float regs = 0.0f, sigs = 0.0f;
        for (int i = threadIdx.x; i < 1024; i += 256) {
            const float4 m4 = mub[i];
            regs += m4.x * m4.x + m4.y * m4.y + m4.z * m4.z + m4.w * m4.w;
            const float4 s4 = sgb[i];
            sigs += 1.0f / s4.x + 1.0f / s4.y + 1.0f / s4.z + 1.0f / s4.w;
        }
        #pragma unroll
        for (int off = 32; off; off >>= 1) {
            regs += __shfl_xor(regs, off);
            sigs += __shfl_xor(sigs, off);
        }
        __shared__ float wr[4], wsg[4];
        const int w = threadIdx.x >> 6;
        if ((threadIdx.x & 63) == 0) { wr[w] = regs; wsg[w] = sigs; }
        __syncthreads();
        if (threadIdx.x == 0) {
            partials[blockIdx.x * 2 + 0] = wr[0] + wr[1] + wr[2] + wr[3];
            partials[blockIdx.x * 2 + 1] = wsg[0] + wsg[1] + wsg[2] + wsg[3];
        }
        return;
    }

    const int wid  = (blockIdx.x - NRED) * 4 + (threadIdx.x >> 6);  // [0, 8192)
    const int lane = threadIdx.x & 63;
    const int r    = lane & 31;
    const int half = lane >> 5;
    const int b    = wid >> 11;                  // / (P * P/2)
    const int rem  = wid & 2047;
    const int g    = rem >> 5;
    const int p    = ((rem & 31) << 1) | half;

    const int mg = mask[(b * P + g) * V + r];
    const int mp = mask[(b * P + p) * V + r];
    const unsigned long long bg = __ballot(mg == 0);
    const unsigned long long bp = __ballot(mp == 0);
    const int nvg = __popcll(bg & 0xffffffffULL);            // wave-uniform
    const int nvp = half ? __popcll(bp >> 32) : __popcll(bp & 0xffffffffULL);
    const int mn  = (nvg < nvp) ? nvg : nvp;                 // per-half uniform
    const bool is_poly = (cls[b * P + g] == 1);              // wave-uniform

    // Register cache of gt row (replicated in both halves): lane L holds gt[g][L&31]
    const float2 gv = ((const float2*)(gt + (size_t)(b * P + g) * (V * 2)))[r];
    const float2* prp2 = (const float2*)(pred + (size_t)(b * P + p) * (V * 2));

    const int mn_other = __shfl_xor(mn, 32);
    const int loopN = (mn > mn_other) ? mn : mn_other;       // wave-uniform

    float s = 0.0f;
    if (is_poly) {
        for (int v = 0; v < loopN; ++v) {
            int idx = r + v;                                 // (r+v) mod nvg for valid lanes
            idx -= (idx >= nvg) ? nvg : 0;
            const float gx = __shfl(gv.x, idx);
            const float gy = __shfl(gv.y, idx);
            const float2 pvv = prp2[v];                      // half-uniform broadcast load
            if (v < mn) s += fabsf(gx - pvv.x) + fabsf(gy - pvv.y);
        }
    } else {
        for (int v = 0; v < loopN; ++v) {
            const int idx = (r == 1) ? (V - 1 - v) : v;
            const float gx = __shfl(gv.x, idx);
            const float gy = __shfl(gv.y, idx);
            const float2 pvv = prp2[v];
            if (v < mn) s += fabsf(gx - pvv.x) + fabsf(gy - pvv.y);
        }
    }

    const bool valid = (mn > 0) && (is_poly ? (r < nvg) : (r < 2));
    float cost_r = valid ? s / (2.0f * (float)mn) : INFINITY;

    #pragma unroll
    for (int off = 16; off; off >>= 1)
        cost_r = fminf(cost_r, __shfl_xor(cost_r, off));
    if (r == 0) costs[(size_t)(b * P + g) * P + p] = cost_r;
}

// One block per batch b. Only touches the 16 KB costs tile + 32 partial floats.
// Quarter-split: thread t handles row/col g = t&63 over 16 p's (q = t>>6).
__global__ __launch_bounds__(256) void finish_kernel(
    const float* __restrict__ ws,
    float*       __restrict__ out)    // 5 * B
{
    const int b = blockIdx.x;
    const int t = threadIdx.x;
    const float* cb       = ws + (size_t)b * P * P;
    const float* partials = ws + B * P * P;

    __shared__ float sc[P][P + 1];     // +1 pad: row reads (g+p)%32 -> conflict-free
    __shared__ float diag[P];
    __shared__ float rmq[4][P], cmq[4][P];
    __shared__ unsigned brq[4];

    {
        const float4* cb4 = (const float4*)cb;
        for (int i = t; i < P * P / 4; i += 256) {
            const float4 v4 = cb4[i];
            const int base = i * 4;
            const int row = base >> 6, col = base & 63;
            sc[row][col + 0] = v4.x;
            sc[row][col + 1] = v4.y;
            sc[row][col + 2] = v4.z;
            sc[row][col + 3] = v4.w;
        }
    }
    __syncthreads();
    if (t < P) diag[t] = sc[t][t];
    __syncthreads();

    const int g = t & 63;
    const int q = t >> 6;
    const float dg = diag[g];
    float rm = 0.0f, cm = 0.0f;     // fmax vs 0 baseline == reference's max(...,0)
    bool  br = false;
    for (int i = 0; i < 16; ++i) {
        const int p = q * 16 + i;
        if (p == g) continue;
        const float cgp = sc[g][p];   // row g
        const float cpg = sc[p][g];   // column g
        rm = fmaxf(rm, MARGIN - cgp + dg);
        cm = fmaxf(cm, MARGIN - cpg + dg);
        br = br || ((cgp < dg) && (cpg < diag[p]));
    }
    rmq[q][g] = rm;
    cmq[q][g] = cm;
    const unsigned long long bb = __ballot(br);
    if ((t & 63) == 0) brq[q] = (bb != 0ULL) ? 1u : 0u;
    __syncthreads();

    if (t < P) {
        const float rmax = fmaxf(fmaxf(rmq[0][t], rmq[1][t]), fmaxf(rmq[2][t], rmq[3][t]));
        const float cmax = fmaxf(fmaxf(cmq[0][t], cmq[1][t]), fmaxf(cmq[2][t], cmq[3][t]));
        float val = rmax + cmax;
        float pr = (t < 4) ? partials[(b * 4 + t) * 2 + 0] : 0.0f;
        float ps = (t < 4) ? partials[(b * 4 + t) * 2 + 1] : 0.0f;
        #pragma unroll
        for (int off = 32; off; off >>= 1) {
            val += __shfl_xor(val, off);
            pr  += __shfl_xor(pr,  off);
            ps  += __shfl_xor(ps,  off);
        }
        if (t == 0) {
            const float reg  = pr / (float)P;
            const float sig  = ps / (float)(P * D);
            const float perm = val;
            out[0 * B + b] = L_REG * reg + L_SIGMA * sig + perm;
            out[1 * B + b] = perm;
            out[2 * B + b] = reg;
            out[3 * B + b] = sig;
            out[4 * B + b] = (brq[0] | brq[1] | brq[2] | brq[3]) ? 1.0f : 0.0f;
        }
    }
}
} // namespace

extern "C" void kernel_launch(void* const* d_in, const int* in_sizes, int n_in,
                              void* d_out, int out_size, void* d_ws, size_t ws_size,
                              hipStream_t stream) {
    const float* gt    = (const float*)d_in[0];
    const float* pred  = (const float*)d_in[1];
    const float* mu    = (const float*)d_in[2];
    const float* sigma = (const float*)d_in[3];
    const int*   mask  = (const int*)d_in[4];
    const int*   cls   = (const int*)d_in[5];
    float* out = (float*)d_out;
    float* ws  = (float*)d_ws;   // B*P*P + NRED*2 floats, fully overwritten

    costs_kernel<<<NRED + B * P * (P / 2) / 4, 256, 0, stream>>>(
        gt, pred, mask, cls, mu, sigma, ws);
    finish_kernel<<<B, 256, 0, stream>>>(ws, out);
}

// Round 2
// 72.397 us; speedup vs baseline: 1.2010x; 1.0083x over previous
//
#include <hip/hip_runtime.h>
#include <math.h>

namespace {
constexpr int B = 4, P = 64, V = 32, D = 256;
constexpr float MARGIN = 0.1f;
constexpr float L_REG = 0.1f, L_SIGMA = 0.05f;
constexpr int NRED = 64;  // blocks that ALSO carry a mu/sigma partial reduction (16/batch)

// ws layout: [0, B*P*P)            costs (B,P,P)
//            [B*P*P, B*P*P+NRED*2) mu/sigma partials: (block)*2 + {reg,sig}

// Grid = exactly 2048 blocks (= 256 CU x 8 blocks/CU at 256 thr, one clean round).
// One wave per (b,g,p-pair): lanes 0-31 -> p0, lanes 32-63 -> p1, r = lane&31.
// gt via register cache + shuffles; pred via half-uniform global_load_dwordx4
// (broadcast, L1-hit after first line). Inner loop unrolled x2, dual accumulators.
// Blocks 0..63 additionally reduce an 8 KB slice of mu/sigma (2 float4/thread).
__global__ __launch_bounds__(256, 8) void costs_kernel(
    const float* __restrict__ gt,    // (B,P,V,2)
    const float* __restrict__ pred,  // (B,P,V,2)
    const int*   __restrict__ mask,  // (B,P,V)
    const int*   __restrict__ cls,   // (B,P)
    const float* __restrict__ mu,    // (B,P,D)
    const float* __restrict__ sigma, // (B,P,D)
    float*       __restrict__ ws)
{
    float* costs    = ws;
    float* partials = ws + B * P * P;

    const int wid  = blockIdx.x * 4 + (threadIdx.x >> 6);   // [0, 8192)
    const int lane = threadIdx.x & 63;
    const int r    = lane & 31;
    const int half = lane >> 5;
    const int b    = wid >> 11;                  // / (P * P/2)
    const int rem  = wid & 2047;
    const int g    = rem >> 5;
    const int p    = ((rem & 31) << 1) | half;

    const int mg = mask[(b * P + g) * V + r];
    const int mp = mask[(b * P + p) * V + r];
    const unsigned long long bg = __ballot(mg == 0);
    const unsigned long long bp = __ballot(mp == 0);
    const int nvg = __popcll(bg & 0xffffffffULL);            // wave-uniform
    const int nvp = half ? __popcll(bp >> 32) : __popcll(bp & 0xffffffffULL);
    const int mn  = (nvg < nvp) ? nvg : nvp;                 // per-half uniform
    const bool is_poly = (cls[b * P + g] == 1);              // wave-uniform

    // Register cache of gt row (replicated in both halves): lane L holds gt[g][L&31]
    const float2 gv = ((const float2*)(gt + (size_t)(b * P + g) * (V * 2)))[r];
    const float4* prp4 = (const float4*)(pred + (size_t)(b * P + p) * (V * 2));

    const int mn_other = __shfl_xor(mn, 32);
    const int loopN = (mn > mn_other) ? mn : mn_other;       // wave-uniform

    float s0 = 0.0f, s1 = 0.0f;
    if (is_poly) {
        for (int v = 0; v < loopN; v += 2) {
            const float4 pv = prp4[v >> 1];                  // pred[v], pred[v+1]
            int i0 = r + v;                                  // (r+v) mod nvg, valid lanes
            i0 -= (i0 >= nvg) ? nvg : 0;
            int i1 = i0 + 1;
            i1 -= (i1 >= nvg) ? nvg : 0;
            const float gx0 = __shfl(gv.x, i0);
            const float gy0 = __shfl(gv.y, i0);
            const float gx1 = __shfl(gv.x, i1);
            const float gy1 = __shfl(gv.y, i1);
            if (v < mn)     s0 += fabsf(gx0 - pv.x) + fabsf(gy0 - pv.y);
            if (v + 1 < mn) s1 += fabsf(gx1 - pv.z) + fabsf(gy1 - pv.w);
        }
    } else {
        const bool rev = (r == 1);
        for (int v = 0; v < loopN; v += 2) {
            const float4 pv = prp4[v >> 1];
            const int i0 = rev ? (V - 1 - v) : v;
            const int i1 = rev ? (V - 2 - v) : (v + 1);      // garbage ok when discarded
            const float gx0 = __shfl(gv.x, i0);
            const float gy0 = __shfl(gv.y, i0);
            const float gx1 = __shfl(gv.x, i1);
            const float gy1 = __shfl(gv.y, i1);
            if (v < mn)     s0 += fabsf(gx0 - pv.x) + fabsf(gy0 - pv.y);
            if (v + 1 < mn) s1 += fabsf(gx1 - pv.z) + fabsf(gy1 - pv.w);
        }
    }
    const float s = s0 + s1;

    const bool valid = (mn > 0) && (is_poly ? (r < nvg) : (r < 2));
    float cost_r = valid ? s / (2.0f * (float)mn) : INFINITY;

    #pragma unroll
    for (int off = 16; off; off >>= 1)
        cost_r = fminf(cost_r, __shfl_xor(cost_r, off));
    if (r == 0) costs[(size_t)(b * P + g) * P + p] = cost_r;

    // Folded mu/sigma partial reduction: blocks 0..63, 8 KB slice each.
    if (blockIdx.x < NRED) {
        const int rb = blockIdx.x >> 4;                      // batch
        const int k  = blockIdx.x & 15;                      // 16 slices per batch
        const float4* mub = (const float4*)(mu    + (size_t)rb * P * D) + k * 256;
        const float4* sgb = (const float4*)(sigma + (size_t)rb * P * D) + k * 256;
        const float4 m4 = mub[threadIdx.x];
        const float4 q4 = sgb[threadIdx.x];
        float regs = m4.x * m4.x + m4.y * m4.y + m4.z * m4.z + m4.w * m4.w;
        float sigs = 1.0f / q4.x + 1.0f / q4.y + 1.0f / q4.z + 1.0f / q4.w;
        #pragma unroll
        for (int off = 32; off; off >>= 1) {
            regs += __shfl_xor(regs, off);
            sigs += __shfl_xor(sigs, off);
        }
        __shared__ float wr[4], wsg[4];
        const int w = threadIdx.x >> 6;
        if ((threadIdx.x & 63) == 0) { wr[w] = regs; wsg[w] = sigs; }
        __syncthreads();
        if (threadIdx.x == 0) {
            partials[blockIdx.x * 2 + 0] = wr[0] + wr[1] + wr[2] + wr[3];
            partials[blockIdx.x * 2 + 1] = wsg[0] + wsg[1] + wsg[2] + wsg[3];
        }
    }
}

// One block per batch b. Only touches the 16 KB costs tile + 128 partial floats.
// Quarter-split: thread t handles row/col g = t&63 over 16 p's (q = t>>6).
__global__ __launch_bounds__(256) void finish_kernel(
    const float* __restrict__ ws,
    float*       __restrict__ out)    // 5 * B
{
    const int b = blockIdx.x;
    const int t = threadIdx.x;
    const float* cb       = ws + (size_t)b * P * P;
    const float* partials = ws + B * P * P;

    __shared__ float sc[P][P + 1];     // +1 pad: row reads (g+p)%32 -> conflict-free
    __shared__ float diag[P];
    __shared__ float rmq[4][P], cmq[4][P];
    __shared__ unsigned brq[4];

    {
        const float4* cb4 = (const float4*)cb;
        for (int i = t; i < P * P / 4; i += 256) {
            const float4 v4 = cb4[i];
            const int base = i * 4;
            const int row = base >> 6, col = base & 63;
            sc[row][col + 0] = v4.x;
            sc[row][col + 1] = v4.y;
            sc[row][col + 2] = v4.z;
            sc[row][col + 3] = v4.w;
        }
    }
    __syncthreads();
    if (t < P) diag[t] = sc[t][t];
    __syncthreads();

    const int g = t & 63;
    const int q = t >> 6;
    const float dg = diag[g];
    float rm = 0.0f, cm = 0.0f;     // fmax vs 0 baseline == reference's max(...,0)
    bool  br = false;
    for (int i = 0; i < 16; ++i) {
        const int p = q * 16 + i;
        if (p == g) continue;
        const float cgp = sc[g][p];   // row g
        const float cpg = sc[p][g];   // column g
        rm = fmaxf(rm, MARGIN - cgp + dg);
        cm = fmaxf(cm, MARGIN - cpg + dg);
        br = br || ((cgp < dg) && (cpg < diag[p]));
    }
    rmq[q][g] = rm;
    cmq[q][g] = cm;
    const unsigned long long bb = __ballot(br);
    if ((t & 63) == 0) brq[q] = (bb != 0ULL) ? 1u : 0u;
    __syncthreads();

    if (t < P) {
        const float rmax = fmaxf(fmaxf(rmq[0][t], rmq[1][t]), fmaxf(rmq[2][t], rmq[3][t]));
        const float cmax = fmaxf(fmaxf(cmq[0][t], cmq[1][t]), fmaxf(cmq[2][t], cmq[3][t]));
        float val = rmax + cmax;
        float pr = (t < 16) ? partials[(b * 16 + t) * 2 + 0] : 0.0f;
        float ps = (t < 16) ? partials[(b * 16 + t) * 2 + 1] : 0.0f;
        #pragma unroll
        for (int off = 32; off; off >>= 1) {
            val += __shfl_xor(val, off);
            pr  += __shfl_xor(pr,  off);
            ps  += __shfl_xor(ps,  off);
        }
        if (t == 0) {
            const float reg  = pr / (float)P;
            const float sig  = ps / (float)(P * D);
            const float perm = val;
            out[0 * B + b] = L_REG * reg + L_SIGMA * sig + perm;
            out[1 * B + b] = perm;
            out[2 * B + b] = reg;
            out[3 * B + b] = sig;
            out[4 * B + b] = (brq[0] | brq[1] | brq[2] | brq[3]) ? 1.0f : 0.0f;
        }
    }
}
} // namespace

extern "C" void kernel_launch(void* const* d_in, const int* in_sizes, int n_in,
                              void* d_out, int out_size, void* d_ws, size_t ws_size,
                              hipStream_t stream) {
    const float* gt    = (const float*)d_in[0];
    const float* pred  = (const float*)d_in[1];
    const float* mu    = (const float*)d_in[2];
    const float* sigma = (const float*)d_in[3];
    const int*   mask  = (const int*)d_in[4];
    const int*   cls   = (const int*)d_in[5];
    float* out = (float*)d_out;
    float* ws  = (float*)d_ws;   // B*P*P + NRED*2 floats, fully overwritten

    costs_kernel<<<B * P * (P / 2) / 4, 256, 0, stream>>>(
        gt, pred, mask, cls, mu, sigma, ws);
    finish_kernel<<<B, 256, 0, stream>>>(ws, out);
}